// Round 3
// baseline (149.239 us; speedup 1.0000x reference)
//
#include <hip/hip_runtime.h>
#include <math.h>

// Hausdorff distance, B=16, N=4096, D=3, fp32.
// out[b] = 0.5*(max_gt min_pred d + max_pred min_gt d), d = ||p-q||^2
//
// R3:
//  - asm-pinned loop structure: R2's VGPR_Count=36 proved the compiler
//    loop-exchanged (k-outer) and re-read q[j] from LDS per home point
//    (8x the intended ds_read traffic). The empty asm volatile on the
//    staged q components makes them opaque VGPRs, forcing j-outer with
//    one ds_read_b128 per 32 VALU.
//  - final reduction fused into the scan kernel (last-block pattern,
//    device-scope fences + agent-scope loads): 3 dispatches -> 2.
//  - half-distance dot form: 3 FMA + 1 min = 4 VALU/pair; hp folded in
//    after the loop; clamp >=0 keeps uint-bit atomicMin ordering exact.

#define NPTS 4096
#define NB 16
#define TPB 256
#define M 8                    // home points per thread
#define SPLIT 16               // opponent chunks
#define HT (TPB * M)           // 2048 home points per block
#define OC (NPTS / SPLIT)      // 256 opponent points per chunk
#define NHT (NPTS / HT)        // 2 home tiles
#define BLOCKS_PER_DB (NHT * SPLIT)   // 32 blocks per (dir, b)

// ws layout (uints): wsmin[2][NB][NPTS], then ctr1[32], ctr2, partial[32]
#define WSMIN_N (2 * NB * NPTS)
#define CTR1_OFF WSMIN_N
#define CTR2_OFF (WSMIN_N + 32)
#define PART_OFF (WSMIN_N + 33)

__global__ __launch_bounds__(TPB) void init_ws_kernel(unsigned int* ws) {
    if (blockIdx.x < WSMIN_N / TPB) {
        ws[(size_t)blockIdx.x * TPB + threadIdx.x] = 0x7F800000u;  // +inf
    } else if (threadIdx.x < 33) {
        ws[CTR1_OFF + threadIdx.x] = 0u;                           // ctr1[32] + ctr2
    }
}

__global__ __launch_bounds__(TPB) void haus_scan_kernel(
        const float* __restrict__ preds, const float* __restrict__ gts,
        unsigned int* __restrict__ ws, float* __restrict__ out) {
    const int ht  = blockIdx.x & (NHT - 1);    // home tile index
    const int oc  = blockIdx.x >> 1;           // opponent chunk index (NHT==2)
    const int b   = blockIdx.y;
    const int dir = blockIdx.z;                // 0: home=gts scan preds; 1: home=preds scan gts
    const int t   = threadIdx.x;

    const float* home = (dir == 0) ? gts : preds;
    const float* opp  = (dir == 0) ? preds : gts;
    const float* hb = home + (size_t)b * NPTS * 3;
    const float* ob = opp  + (size_t)b * NPTS * 3;

    // stage opponent chunk: (qx,qy,qz, hq=|q|^2/2)
    __shared__ float4 q[OC];
    {
        const float* src = ob + (size_t)(oc * OC + t) * 3;
        float qx = src[0], qy = src[1], qz = src[2];
        float hq = 0.5f * fmaf(qx, qx, fmaf(qy, qy, qz * qz));
        q[t] = make_float4(qx, qy, qz, hq);
    }

    float px[M], py[M], pz[M], best[M];
#pragma unroll
    for (int k = 0; k < M; ++k) {
        int hi = ht * HT + k * TPB + t;
        px[k] = hb[hi * 3 + 0];
        py[k] = hb[hi * 3 + 1];
        pz[k] = hb[hi * 3 + 2];
        best[k] = INFINITY;
    }

    __syncthreads();

#pragma unroll 4
    for (int j = 0; j < OC; ++j) {
        float4 q4 = q[j];                      // wave-uniform -> ds_read_b128 broadcast
        float qx = q4.x, qy = q4.y, qz = q4.z, qw = q4.w;
        // opaque barrier: pins qx..qw in VGPRs so the compiler cannot
        // loop-exchange and re-read LDS once per home point (R2 bug).
        asm volatile("" : "+v"(qx), "+v"(qy), "+v"(qz), "+v"(qw));
#pragma unroll
        for (int k = 0; k < M; ++k) {
            float acc = fmaf(-px[k], qx, qw);  // hq - p.q (half sq-dist - hp)
            acc = fmaf(-py[k], qy, acc);
            acc = fmaf(-pz[k], qz, acc);
            best[k] = fminf(best[k], acc);
        }
    }

    unsigned int* slot = ws + ((size_t)dir * NB + b) * NPTS + ht * HT;
#pragma unroll
    for (int k = 0; k < M; ++k) {
        int hi = ht * HT + k * TPB + t;
        float hp = 0.5f * fmaf(px[k], px[k], fmaf(py[k], py[k], pz[k] * pz[k]));
        float d2 = fmaxf(best[k] + hp, 0.0f);  // >=0 so uint order == float order
        atomicMin(slot - ht * HT + hi, __float_as_uint(d2));
    }

    // ---- fused reduction: last block per (dir,b), then global last ----
    __threadfence();                            // release this thread's atomics
    __shared__ bool s_last;
    __syncthreads();
    if (t == 0) {
        unsigned old = atomicAdd(&ws[CTR1_OFF + dir * NB + b], 1u);
        s_last = (old == BLOCKS_PER_DB - 1);
    }
    __syncthreads();
    if (!s_last) return;

    __threadfence();                            // acquire
    const unsigned int* basep = ws + ((size_t)dir * NB + b) * NPTS;
    unsigned mx = 0u;
#pragma unroll
    for (int r = 0; r < NPTS / TPB; ++r) {      // 16 per thread
        unsigned v = __hip_atomic_load(&basep[r * TPB + t], __ATOMIC_RELAXED,
                                       __HIP_MEMORY_SCOPE_AGENT);
        mx = mx > v ? mx : v;                   // uint max == float max (vals >= 0)
    }
#pragma unroll
    for (int off = 32; off > 0; off >>= 1) {
        unsigned o = (unsigned)__shfl_down((int)mx, off, 64);
        mx = mx > o ? mx : o;
    }
    __shared__ unsigned sred[4];
    if ((t & 63) == 0) sred[t >> 6] = mx;
    __syncthreads();                            // (A)
    if (t == 0) {
        unsigned m01 = sred[0] > sred[1] ? sred[0] : sred[1];
        unsigned m23 = sred[2] > sred[3] ? sred[2] : sred[3];
        unsigned m = m01 > m23 ? m01 : m23;
        __hip_atomic_store(&ws[PART_OFF + dir * NB + b], m, __ATOMIC_RELAXED,
                           __HIP_MEMORY_SCOPE_AGENT);
        __threadfence();                        // release partial
        unsigned old2 = atomicAdd(&ws[CTR2_OFF], 1u);
        s_last = (old2 == 2 * NB - 1);
    }
    __syncthreads();                            // (B)
    if (!s_last) return;

    __threadfence();                            // acquire partials
    if (t < NB) {
        unsigned u0 = __hip_atomic_load(&ws[PART_OFF + 0 * NB + t], __ATOMIC_RELAXED,
                                        __HIP_MEMORY_SCOPE_AGENT);
        unsigned u1 = __hip_atomic_load(&ws[PART_OFF + 1 * NB + t], __ATOMIC_RELAXED,
                                        __HIP_MEMORY_SCOPE_AGENT);
        // values are half squared distances: sum == 0.5*(loss1+loss2)
        out[t] = __uint_as_float(u0) + __uint_as_float(u1);
    }
}

extern "C" void kernel_launch(void* const* d_in, const int* in_sizes, int n_in,
                              void* d_out, int out_size, void* d_ws, size_t ws_size,
                              hipStream_t stream) {
    const float* preds = (const float*)d_in[0];
    const float* gts   = (const float*)d_in[1];
    float* out = (float*)d_out;
    unsigned int* ws = (unsigned int*)d_ws;     // 512 KB + 65 uints used

    init_ws_kernel<<<dim3(WSMIN_N / TPB + 1), dim3(TPB), 0, stream>>>(ws);

    haus_scan_kernel<<<dim3(NHT * SPLIT, NB, 2), dim3(TPB), 0, stream>>>(
        preds, gts, ws, out);
}